// Round 13
// baseline (207.274 us; speedup 1.0000x reference)
//
#include <hip/hip_runtime.h>

// GNN: 2x SAGEConv(sum) + global_add_pool + Linear head.
// N=50000 nodes, E=1e6 edges, D=H=64, G=512 graphs, O=16.
//
// R1: CSR gather replaced scatter atomics (2111 -> 606 us).
// R2: sorted-segment pooling replaced atomic pooling (606 -> 395 us).
// R3: binned counting sort for CSR build (395 -> 367 us).
// R4: bf16 feature storage, fp32 accumulate (367 -> 325 us).
// R5: bucket-local degree counting (325 -> 302 us).
// R6: scan-free CSR; grid-stride GEMM regressed (net wash).
// R7: MFMA GEMM, K=128 N=64 bf16 16x16x32 (305 -> 240 us).
// R8/R9: gather XCD experiments — full-machine 8x-dup gather is the floor.
// R10: LDS-presort scatter + pooling fused into GEMM-2 (240 -> 197 us).
// R11: gather fused into MFMA GEMM (197 -> 193; under-delivered: the
//      fragment-shaped gather used 4 lanes x 2 split 16B loads per line =
//      2x the L1 transaction rate of the full-line shape).
// R12: fused gather restructured to the proven full-line shape: 2 passes
// of 8 rows x 8 lanes/row (one uint4 instr = 8 fully-consumed 128B lines),
// then wave-local LDS redistribution (2x ds_write_b128 + 2x ds_read_b128
// per lane, no barrier: wave-lockstep, in-order DS pipe) into MFMA
// A-fragments. Byte traffic unchanged; transaction rate halved.

namespace {
constexpr int NN = 50000;
constexpr int NE = 1000000;
constexpr int NG = 512;
constexpr int NO = 16;
constexpr int KB = 98;                      // buckets: dst>>9 (512 nodes)
constexpr int BCAP = 16000;                 // slot capacity per bucket
constexpr int EPT = 8;                      // edges per thread (scatter)
constexpr int EPB = 256 * EPT;              // 2048 edges per block
constexpr int SBLK = (NE + EPB - 1) / EPB;  // 489 scatter blocks
constexpr int SEDGE = 12288;                // staged edges in bucket_sort
constexpr int CVT_BLK = (NN * 64 / 8 + 255) / 256;  // 1563 cvt blocks
constexpr int WP_BLK = 64;                  // weight-prep blocks
}

typedef __attribute__((ext_vector_type(8))) short bf16x8;
typedef __attribute__((ext_vector_type(4))) float f32x4;

__device__ __forceinline__ unsigned short f2bf(float f) {
  unsigned u = __float_as_uint(f);
  u += 0x7FFFu + ((u >> 16) & 1u);  // round-to-nearest-even
  return (unsigned short)(u >> 16);
}

// ---------- prep: x->bf16 | weight transpose | bucket scatter (one launch) --
__global__ __launch_bounds__(256) void prep_all(
    const float* __restrict__ x, unsigned short* __restrict__ x_bf,
    const float* __restrict__ Wl1, const float* __restrict__ Wr1,
    const float* __restrict__ Wl2, const float* __restrict__ Wr2,
    unsigned short* __restrict__ Wt1, unsigned short* __restrict__ Wt2,
    const int* __restrict__ ei, int* __restrict__ bcount,
    unsigned int* __restrict__ ebuf) {
  __shared__ unsigned int stage[EPB];  // 8 KB (scatter role)
  __shared__ int cnt[128];
  __shared__ int lbase[128];
  __shared__ int cur[128];
  __shared__ int gbase[128];
  __shared__ int total_sh;
  int b = blockIdx.x;
  int t = threadIdx.x;

  if (b < CVT_BLK) {  // ---- x -> bf16
    int i = b * 256 + t;
    if (i >= NN * 8) return;
    const float4* p = reinterpret_cast<const float4*>(x) + (size_t)i * 2;
    float4 a = p[0], bb = p[1];
    uint4 u;
    u.x = (unsigned)f2bf(a.x) | ((unsigned)f2bf(a.y) << 16);
    u.y = (unsigned)f2bf(a.z) | ((unsigned)f2bf(a.w) << 16);
    u.z = (unsigned)f2bf(bb.x) | ((unsigned)f2bf(bb.y) << 16);
    u.w = (unsigned)f2bf(bb.z) | ((unsigned)f2bf(bb.w) << 16);
    reinterpret_cast<uint4*>(x_bf)[i] = u;
    return;
  }
  if (b < CVT_BLK + WP_BLK) {  // ---- Wt[n][kk] transpose, both layers
    int id = (b - CVT_BLK) * 256 + t;  // 16384 total
    int half = id >> 13;
    int e = id & 8191;
    int nrow = e >> 7;
    int kk = e & 127;
    const float* Wl = half ? Wl2 : Wl1;
    const float* Wr = half ? Wr2 : Wr1;
    unsigned short* Wt = half ? Wt2 : Wt1;
    float v = (kk < 64) ? Wl[kk * 64 + nrow] : Wr[(kk - 64) * 64 + nrow];
    Wt[nrow * 128 + kk] = f2bf(v);
    return;
  }
  // ---- bucket scatter (LDS presort, coalesced run copy-out)
  int sb = b - (CVT_BLK + WP_BLK);
  if (t < 128) cnt[t] = 0;
  __syncthreads();
  int e0 = sb * EPB;
  unsigned int pk[EPT];
#pragma unroll
  for (int i = 0; i < EPT; ++i) {
    int e = e0 + i * 256 + t;
    if (e < NE) {
      unsigned int src = (unsigned int)ei[e];
      unsigned int dst = (unsigned int)ei[NE + e];
      pk[i] = (dst << 16) | src;
      atomicAdd(&cnt[dst >> 9], 1);
    } else {
      pk[i] = 0xFFFFFFFFu;
    }
  }
  __syncthreads();
  int deg = (t < 128) ? cnt[t] : 0;
  for (int off = 1; off < 128; off <<= 1) {
    int u = (t >= off && t < 128) ? cnt[t - off] : 0;
    __syncthreads();
    if (t < 128) cnt[t] += u;
    __syncthreads();
  }
  if (t < 128) {
    int excl = cnt[t] - deg;
    lbase[t] = excl;
    cur[t] = excl;
    if (t < KB) gbase[t] = t * BCAP + atomicAdd(&bcount[t], deg);
    if (t == 127) total_sh = cnt[127];
  }
  __syncthreads();
#pragma unroll
  for (int i = 0; i < EPT; ++i) {
    if (pk[i] != 0xFFFFFFFFu) {
      int bb2 = pk[i] >> 25;  // dst >> 9
      int s = atomicAdd(&cur[bb2], 1);
      stage[s] = pk[i];
    }
  }
  __syncthreads();
  int total = total_sh;
  for (int s = t; s < total; s += 256) {
    unsigned int p = stage[s];
    int bb2 = p >> 25;
    ebuf[gbase[bb2] + (s - lbase[bb2])] = p;
  }
}

// One 512-thread block per bucket: LDS hist + scan + place into col
// (ushort, bucket window), emit meta[node] = (col_beg << 11) | deg.
__global__ __launch_bounds__(512) void bucket_sort(
    const unsigned int* __restrict__ ebuf, const int* __restrict__ bcount,
    unsigned int* __restrict__ meta, unsigned short* __restrict__ col) {
  __shared__ unsigned int se[SEDGE];  // 48 KB edge stage
  __shared__ int cnt[512];
  __shared__ int cur[512];
  int b = blockIdx.x;
  int t = threadIdx.x;
  int n = bcount[b];
  const unsigned int* eb = ebuf + (size_t)b * BCAP;
  cnt[t] = 0;
  __syncthreads();
  for (int j = t; j < n; j += 512) {
    unsigned int p = eb[j];
    if (j < SEDGE) se[j] = p;
    atomicAdd(&cnt[(p >> 16) & 511], 1);
  }
  __syncthreads();
  int deg = cnt[t];
  for (int off = 1; off < 512; off <<= 1) {
    int u = (t >= off) ? cnt[t - off] : 0;
    __syncthreads();
    cnt[t] += u;
    __syncthreads();
  }
  int excl = cnt[t] - deg;
  cur[t] = excl;
  int node = (b << 9) + t;
  if (node < NN) {
    meta[node] = ((unsigned)(b * BCAP + excl) << 11) | (unsigned)deg;
  }
  __syncthreads();
  unsigned short* cb = col + (size_t)b * BCAP;
  for (int j = t; j < n; j += 512) {
    unsigned int p = (j < SEDGE) ? se[j] : eb[j];
    int d = (p >> 16) & 511;
    int pos = atomicAdd(&cur[d], 1);
    cb[pos] = (unsigned short)(p & 0xFFFFu);
  }
}

// ------------- fused gather + MFMA GEMM (+ optional pooling) ---------------
// out[row,:] = relu( (sum_{s in N(row)} feat[s]) @ Wl + feat[row] @ Wr + b )
// Wave = rows base..base+15.
// GATHER (full-line shape): 2 passes of 8 rows; lane (h=lane>>3, o=lane&7)
// accumulates fp32 chunk o of row base+p*8+h. One uint4 load instruction
// per edge-group touches 8 fully-consumed 128B lines (the R4/R10-proven
// optimal pattern). Results staged bf16 in a per-wave LDS tile.
// REDISTRIBUTE: lane (q=lane>>4, m=lane&15) ds_read_b128's its A-fragments
// af[0..1] from the tile (wave-local: lockstep + in-order DS pipe, no
// barrier). af[2..3] = root term, loaded from feat[row].
// MFMA: 16x v_mfma_f32_16x16x32_bf16 vs Wt (L1-resident), bias in acc.
// POOL=true: relu tile -> LDS, sorted-batch segment walk, spread atomics.
template <bool POOL>
__global__ __launch_bounds__(256) void sage_fused(
    const unsigned short* __restrict__ feat,
    const unsigned int* __restrict__ meta,
    const unsigned short* __restrict__ col,
    const unsigned short* __restrict__ Wt, const float* __restrict__ bias,
    unsigned short* __restrict__ out, const int* __restrict__ batch,
    float* __restrict__ pooled) {
  __shared__ __align__(16) unsigned short tile[4][16][72];  // 9 KB
  __shared__ float psm[POOL ? 4 : 1][16][64];               // 16 KB if POOL
  int tid = threadIdx.x;
  int wave = tid >> 6;
  int lane = tid & 63;
  long base = ((long)blockIdx.x * 4 + wave) * 16;
  bool active = (base < NN);
  if (!POOL && !active) return;

  int m = lane & 15;
  int q = lane >> 4;

  if (active) {
    // ---- gather phase: full-line shape, 2 passes of 8 rows
    int h = lane >> 3;  // row-in-pass
    int o = lane & 7;   // 16B chunk
    const uint4* fb = reinterpret_cast<const uint4*>(feat);
#pragma unroll
    for (int p = 0; p < 2; ++p) {
      long row = base + p * 8 + h;
      if (row >= NN) row = NN - 1;  // clamped dup work; store predicated
      unsigned int md = meta[row];
      int beg = (int)(md >> 11);
      int deg = (int)(md & 2047u);
      float a0 = 0.f, a1 = 0.f, a2 = 0.f, a3 = 0.f;
      float a4 = 0.f, a5 = 0.f, a6 = 0.f, a7 = 0.f;
      for (int j = 0; j < deg; ++j) {
        int s = col[beg + j];  // broadcast across the row's 8 lanes
        uint4 u = fb[(size_t)s * 8 + o];
        a0 += __uint_as_float(u.x << 16);
        a1 += __uint_as_float(u.x & 0xFFFF0000u);
        a2 += __uint_as_float(u.y << 16);
        a3 += __uint_as_float(u.y & 0xFFFF0000u);
        a4 += __uint_as_float(u.z << 16);
        a5 += __uint_as_float(u.z & 0xFFFF0000u);
        a6 += __uint_as_float(u.w << 16);
        a7 += __uint_as_float(u.w & 0xFFFF0000u);
      }
      uint4 pk;
      pk.x = (unsigned)f2bf(a0) | ((unsigned)f2bf(a1) << 16);
      pk.y = (unsigned)f2bf(a2) | ((unsigned)f2bf(a3) << 16);
      pk.z = (unsigned)f2bf(a4) | ((unsigned)f2bf(a5) << 16);
      pk.w = (unsigned)f2bf(a6) | ((unsigned)f2bf(a7) << 16);
      *reinterpret_cast<uint4*>(&tile[wave][p * 8 + h][o * 8]) = pk;
    }

    // ---- redistribute: A-fragments from the wave-local tile
    bf16x8 af[4];
    af[0] = *reinterpret_cast<const bf16x8*>(&tile[wave][m][q * 8]);
    af[1] = *reinterpret_cast<const bf16x8*>(&tile[wave][m][32 + q * 8]);
    long rowm = base + m;
    if (rowm >= NN) rowm = NN - 1;
    const unsigned short* hrow = feat + rowm * 64;
    af[2] = *(const bf16x8*)(hrow + q * 8);       // k 64..95
    af[3] = *(const bf16x8*)(hrow + 32 + q * 8);  // k 96..127

    // ---- MFMA phase
    f32x4 acc[4];
#pragma unroll
    for (int t = 0; t < 4; ++t) {
      float bv = bias[t * 16 + m];
      acc[t][0] = bv;
      acc[t][1] = bv;
      acc[t][2] = bv;
      acc[t][3] = bv;
    }
#pragma unroll
    for (int t = 0; t < 4; ++t) {
      const unsigned short* wrow = Wt + (size_t)(t * 16 + m) * 128 + q * 8;
#pragma unroll
      for (int s = 0; s < 4; ++s) {
        bf16x8 bfm = *(const bf16x8*)(wrow + s * 32);
        acc[t] = __builtin_amdgcn_mfma_f32_16x16x32_bf16(af[s], bfm, acc[t], 0,
                                                         0, 0);
      }
    }

    // ---- epilogue
    if (POOL) {
#pragma unroll
      for (int r = 0; r < 4; ++r) {
#pragma unroll
        for (int t = 0; t < 4; ++t) {
          psm[wave][q * 4 + r][t * 16 + m] = fmaxf(acc[t][r], 0.f);
        }
      }
    } else {
#pragma unroll
      for (int r = 0; r < 4; ++r) {
        long rowc = base + q * 4 + r;
        if (rowc < NN) {
          unsigned short* orow = out + rowc * 64;
#pragma unroll
          for (int t = 0; t < 4; ++t) {
            orow[t * 16 + m] = f2bf(fmaxf(acc[t][r], 0.f));
          }
        }
      }
    }
  }

  if (POOL) {
    __syncthreads();
    int c = tid & 63;
    int w = tid >> 6;
    long tbase = ((long)blockIdx.x * 4 + w) * 16;
    if (tbase < NN) {
      float run = 0.f;
      int g = batch[tbase];
      for (int i = 0; i < 16; ++i) {
        long rowi = tbase + i;
        if (rowi >= NN) break;
        int gi = batch[rowi];
        if (gi != g) {
          atomicAdd(&pooled[(size_t)g * 64 + c], run);
          run = 0.f;
          g = gi;
        }
        run += psm[w][i][c];
      }
      atomicAdd(&pooled[(size_t)g * 64 + c], run);
    }
  }
}

// ---------------- head: out[g,o] = bo[o] + pooled[g,:] @ Wo[:,o] -----------
__global__ __launch_bounds__(256) void head_kernel(
    const float* __restrict__ pooled, const float* __restrict__ Wo,
    const float* __restrict__ bo, float* __restrict__ out) {
  int id = blockIdx.x * 256 + threadIdx.x;
  if (id >= NG * NO) return;
  int g = id >> 4, o = id & 15;
  float acc = bo[o];
  const float* p = pooled + (size_t)g * 64;
#pragma unroll
  for (int k = 0; k < 64; ++k) acc += p[k] * Wo[k * 16 + o];
  out[id] = acc;
}

extern "C" void kernel_launch(void* const* d_in, const int* in_sizes, int n_in,
                              void* d_out, int out_size, void* d_ws,
                              size_t ws_size, hipStream_t stream) {
  const float* x = (const float*)d_in[0];
  const int* ei = (const int*)d_in[1];
  const int* batch = (const int*)d_in[2];
  const float* Wl1 = (const float*)d_in[3];
  const float* Wr1 = (const float*)d_in[4];
  const float* b1 = (const float*)d_in[5];
  const float* Wl2 = (const float*)d_in[6];
  const float* Wr2 = (const float*)d_in[7];
  const float* b2 = (const float*)d_in[8];
  const float* Wo = (const float*)d_in[9];
  const float* bo = (const float*)d_in[10];
  float* out = (float*)d_out;

  // Workspace (~22.7 MB):
  unsigned short* x_bf = (unsigned short*)d_ws;     // NN*64 bf16 (6.4 MB)
  unsigned short* h1_bf = x_bf + (size_t)NN * 64;   // NN*64 bf16 (6.4 MB)
  unsigned short* col = h1_bf + (size_t)NN * 64;    // KB*BCAP ushort (3.1MB)
  unsigned short* Wt1 = col + (size_t)KB * BCAP;    // 64*128 bf16
  unsigned short* Wt2 = Wt1 + 64 * 128;             // 64*128 bf16
  unsigned int* ebuf = (unsigned int*)(Wt2 + 64 * 128);  // KB*BCAP (6.27MB)
  unsigned int* meta = ebuf + (size_t)KB * BCAP;    // NN
  int* bcount = (int*)(meta + NN);                  // KB
  float* pooled = (float*)(bcount + KB);            // NG*64 (contig w/bcount)

  // one memset covers bcount + pooled (contiguous)
  hipMemsetAsync(bcount, 0, KB * sizeof(int) + (size_t)NG * 64 * sizeof(float),
                 stream);

  const int gemm_blocks = (NN + 63) / 64;  // 782: 4 waves x 16 rows

  // prep: x->bf16 | weight transpose | bucket scatter (one role-split launch)
  prep_all<<<CVT_BLK + WP_BLK + SBLK, 256, 0, stream>>>(
      x, x_bf, Wl1, Wr1, Wl2, Wr2, Wt1, Wt2, ei, bcount, ebuf);

  // CSR finalize
  bucket_sort<<<KB, 512, 0, stream>>>(ebuf, bcount, meta, col);

  // Layer 1: fused gather+GEMM, writes h1
  sage_fused<false><<<gemm_blocks, 256, 0, stream>>>(
      x_bf, meta, col, Wt1, b1, h1_bf, batch, pooled);

  // Layer 2: fused gather+GEMM+pool (h2 never materialized)
  sage_fused<true><<<gemm_blocks, 256, 0, stream>>>(
      h1_bf, meta, col, Wt2, b2, nullptr, batch, pooled);

  // Head from pooled (128 KB)
  head_kernel<<<(NG * NO + 255) / 256, 256, 0, stream>>>(pooled, Wo, bo, out);
}

// Round 14
// 181.839 us; speedup vs baseline: 1.1399x; 1.1399x over previous
//
#include <hip/hip_runtime.h>

// GNN: 2x SAGEConv(sum) + global_add_pool + Linear head.
// N=50000 nodes, E=1e6 edges, D=H=64, G=512 graphs, O=16.
//
// R1: CSR gather replaced scatter atomics (2111 -> 606 us).
// R2: sorted-segment pooling replaced atomic pooling (606 -> 395 us).
// R3: binned counting sort for CSR build (395 -> 367 us).
// R4: bf16 feature storage, fp32 accumulate (367 -> 325 us).
// R5: bucket-local degree counting (325 -> 302 us).
// R6: scan-free CSR; grid-stride GEMM regressed (net wash).
// R7: MFMA GEMM, K=128 N=64 bf16 16x16x32 (305 -> 240 us).
// R8/R9: gather XCD experiments — full-machine 8x-dup gather is the floor.
// R10: LDS-presort scatter + pooling fused into GEMM-2 (240 -> 197 us).
// R11: gather fused into MFMA GEMM (197 -> 193).
// R12: full-line gather inside fused kernel REGRESSED (193 -> 207):
//      2 sequential 8-row passes doubled exposed trips (2xmax8 vs max16);
//      kernel is latency/trip-bound (VALUBusy 11%), not transaction-bound.
// R13: 2-wave cooperative fusion: 1563 blocks x 32 rows; each 16-row group
// is gathered by a PAIR of waves (each wave 8 rows, full-line shape, one
// pass, trip=max8 -> 6252 gather-waves == standalone-gather parallelism),
// tile in LDS, one barrier, then the pair splits MFMA by columns (2
// t-tiles each, 8 acc VGPRs). agg still never materialized.

namespace {
constexpr int NN = 50000;
constexpr int NE = 1000000;
constexpr int NG = 512;
constexpr int NO = 16;
constexpr int KB = 98;                      // buckets: dst>>9 (512 nodes)
constexpr int BCAP = 16000;                 // slot capacity per bucket
constexpr int EPT = 8;                      // edges per thread (scatter)
constexpr int EPB = 256 * EPT;              // 2048 edges per block
constexpr int SBLK = (NE + EPB - 1) / EPB;  // 489 scatter blocks
constexpr int SEDGE = 12288;                // staged edges in bucket_sort
constexpr int CVT_BLK = (NN * 64 / 8 + 255) / 256;  // 1563 cvt blocks
constexpr int WP_BLK = 64;                  // weight-prep blocks
}

typedef __attribute__((ext_vector_type(8))) short bf16x8;
typedef __attribute__((ext_vector_type(4))) float f32x4;

__device__ __forceinline__ unsigned short f2bf(float f) {
  unsigned u = __float_as_uint(f);
  u += 0x7FFFu + ((u >> 16) & 1u);  // round-to-nearest-even
  return (unsigned short)(u >> 16);
}

// ---------- prep: x->bf16 | weight transpose | bucket scatter (one launch) --
__global__ __launch_bounds__(256) void prep_all(
    const float* __restrict__ x, unsigned short* __restrict__ x_bf,
    const float* __restrict__ Wl1, const float* __restrict__ Wr1,
    const float* __restrict__ Wl2, const float* __restrict__ Wr2,
    unsigned short* __restrict__ Wt1, unsigned short* __restrict__ Wt2,
    const int* __restrict__ ei, int* __restrict__ bcount,
    unsigned int* __restrict__ ebuf) {
  __shared__ unsigned int stage[EPB];  // 8 KB (scatter role)
  __shared__ int cnt[128];
  __shared__ int lbase[128];
  __shared__ int cur[128];
  __shared__ int gbase[128];
  __shared__ int total_sh;
  int b = blockIdx.x;
  int t = threadIdx.x;

  if (b < CVT_BLK) {  // ---- x -> bf16
    int i = b * 256 + t;
    if (i >= NN * 8) return;
    const float4* p = reinterpret_cast<const float4*>(x) + (size_t)i * 2;
    float4 a = p[0], bb = p[1];
    uint4 u;
    u.x = (unsigned)f2bf(a.x) | ((unsigned)f2bf(a.y) << 16);
    u.y = (unsigned)f2bf(a.z) | ((unsigned)f2bf(a.w) << 16);
    u.z = (unsigned)f2bf(bb.x) | ((unsigned)f2bf(bb.y) << 16);
    u.w = (unsigned)f2bf(bb.z) | ((unsigned)f2bf(bb.w) << 16);
    reinterpret_cast<uint4*>(x_bf)[i] = u;
    return;
  }
  if (b < CVT_BLK + WP_BLK) {  // ---- Wt[n][kk] transpose, both layers
    int id = (b - CVT_BLK) * 256 + t;  // 16384 total
    int half = id >> 13;
    int e = id & 8191;
    int nrow = e >> 7;
    int kk = e & 127;
    const float* Wl = half ? Wl2 : Wl1;
    const float* Wr = half ? Wr2 : Wr1;
    unsigned short* Wt = half ? Wt2 : Wt1;
    float v = (kk < 64) ? Wl[kk * 64 + nrow] : Wr[(kk - 64) * 64 + nrow];
    Wt[nrow * 128 + kk] = f2bf(v);
    return;
  }
  // ---- bucket scatter (LDS presort, coalesced run copy-out)
  int sb = b - (CVT_BLK + WP_BLK);
  if (t < 128) cnt[t] = 0;
  __syncthreads();
  int e0 = sb * EPB;
  unsigned int pk[EPT];
#pragma unroll
  for (int i = 0; i < EPT; ++i) {
    int e = e0 + i * 256 + t;
    if (e < NE) {
      unsigned int src = (unsigned int)ei[e];
      unsigned int dst = (unsigned int)ei[NE + e];
      pk[i] = (dst << 16) | src;
      atomicAdd(&cnt[dst >> 9], 1);
    } else {
      pk[i] = 0xFFFFFFFFu;
    }
  }
  __syncthreads();
  int deg = (t < 128) ? cnt[t] : 0;
  for (int off = 1; off < 128; off <<= 1) {
    int u = (t >= off && t < 128) ? cnt[t - off] : 0;
    __syncthreads();
    if (t < 128) cnt[t] += u;
    __syncthreads();
  }
  if (t < 128) {
    int excl = cnt[t] - deg;
    lbase[t] = excl;
    cur[t] = excl;
    if (t < KB) gbase[t] = t * BCAP + atomicAdd(&bcount[t], deg);
    if (t == 127) total_sh = cnt[127];
  }
  __syncthreads();
#pragma unroll
  for (int i = 0; i < EPT; ++i) {
    if (pk[i] != 0xFFFFFFFFu) {
      int bb2 = pk[i] >> 25;  // dst >> 9
      int s = atomicAdd(&cur[bb2], 1);
      stage[s] = pk[i];
    }
  }
  __syncthreads();
  int total = total_sh;
  for (int s = t; s < total; s += 256) {
    unsigned int p = stage[s];
    int bb2 = p >> 25;
    ebuf[gbase[bb2] + (s - lbase[bb2])] = p;
  }
}

// One 512-thread block per bucket: LDS hist + scan + place into col
// (ushort, bucket window), emit meta[node] = (col_beg << 11) | deg.
__global__ __launch_bounds__(512) void bucket_sort(
    const unsigned int* __restrict__ ebuf, const int* __restrict__ bcount,
    unsigned int* __restrict__ meta, unsigned short* __restrict__ col) {
  __shared__ unsigned int se[SEDGE];  // 48 KB edge stage
  __shared__ int cnt[512];
  __shared__ int cur[512];
  int b = blockIdx.x;
  int t = threadIdx.x;
  int n = bcount[b];
  const unsigned int* eb = ebuf + (size_t)b * BCAP;
  cnt[t] = 0;
  __syncthreads();
  for (int j = t; j < n; j += 512) {
    unsigned int p = eb[j];
    if (j < SEDGE) se[j] = p;
    atomicAdd(&cnt[(p >> 16) & 511], 1);
  }
  __syncthreads();
  int deg = cnt[t];
  for (int off = 1; off < 512; off <<= 1) {
    int u = (t >= off) ? cnt[t - off] : 0;
    __syncthreads();
    cnt[t] += u;
    __syncthreads();
  }
  int excl = cnt[t] - deg;
  cur[t] = excl;
  int node = (b << 9) + t;
  if (node < NN) {
    meta[node] = ((unsigned)(b * BCAP + excl) << 11) | (unsigned)deg;
  }
  __syncthreads();
  unsigned short* cb = col + (size_t)b * BCAP;
  for (int j = t; j < n; j += 512) {
    unsigned int p = (j < SEDGE) ? se[j] : eb[j];
    int d = (p >> 16) & 511;
    int pos = atomicAdd(&cur[d], 1);
    cb[pos] = (unsigned short)(p & 0xFFFFu);
  }
}

// ---------- fused gather + MFMA GEMM, 2-wave cooperative ----------
// Block = 4 waves = 2 groups of 16 rows (32 rows/block, 1563 blocks).
// GATHER: each wave of a pair gathers 8 rows in the full-line shape
// (lane h=lane>>3 row, o=lane&7 chunk; one uint4 instr = 8 full 128B
// lines; trip = max deg over 8 rows) -> bf16 LDS tile. 6252 gather-waves
// total == the standalone gather's proven parallelism.
// One __syncthreads, then the pair splits MFMA by columns: wave wv does
// t = {2wv, 2wv+1} (8 MFMAs, 8 acc VGPRs). af[2..3] root term from feat.
// POOL=true: relu halves -> psm, second barrier, 128 walkers do the
// sorted-batch segment walk with spread fp32 atomics (R10 scheme).
// NO early returns (barriers must be uniform); work is predicated.
template <bool POOL>
__global__ __launch_bounds__(256) void sage_fused(
    const unsigned short* __restrict__ feat,
    const unsigned int* __restrict__ meta,
    const unsigned short* __restrict__ col,
    const unsigned short* __restrict__ Wt, const float* __restrict__ bias,
    unsigned short* __restrict__ out, const int* __restrict__ batch,
    float* __restrict__ pooled) {
  __shared__ __align__(16) unsigned short tile[2][16][72];  // 4.6 KB
  __shared__ float psm[POOL ? 2 : 1][16][64];               // 8 KB if POOL
  int tid = threadIdx.x;
  int wave = tid >> 6;
  int lane = tid & 63;
  int grp = wave >> 1;  // 16-row group within block
  int wv = wave & 1;    // wave within pair
  long base = ((long)blockIdx.x * 2 + grp) * 16;

  // ---- gather phase: this wave's 8 rows, full-line shape
  {
    int h = lane >> 3;  // row-in-wave
    int o = lane & 7;   // 16B chunk
    long row = base + wv * 8 + h;
    int beg = 0, deg = 0;
    if (row < NN) {
      unsigned int md = meta[row];
      beg = (int)(md >> 11);
      deg = (int)(md & 2047u);
    }
    const uint4* fb = reinterpret_cast<const uint4*>(feat);
    float a0 = 0.f, a1 = 0.f, a2 = 0.f, a3 = 0.f;
    float a4 = 0.f, a5 = 0.f, a6 = 0.f, a7 = 0.f;
    for (int j = 0; j < deg; ++j) {
      int s = col[beg + j];  // broadcast across the row's 8 lanes
      uint4 u = fb[(size_t)s * 8 + o];
      a0 += __uint_as_float(u.x << 16);
      a1 += __uint_as_float(u.x & 0xFFFF0000u);
      a2 += __uint_as_float(u.y << 16);
      a3 += __uint_as_float(u.y & 0xFFFF0000u);
      a4 += __uint_as_float(u.z << 16);
      a5 += __uint_as_float(u.z & 0xFFFF0000u);
      a6 += __uint_as_float(u.w << 16);
      a7 += __uint_as_float(u.w & 0xFFFF0000u);
    }
    uint4 pk;
    pk.x = (unsigned)f2bf(a0) | ((unsigned)f2bf(a1) << 16);
    pk.y = (unsigned)f2bf(a2) | ((unsigned)f2bf(a3) << 16);
    pk.z = (unsigned)f2bf(a4) | ((unsigned)f2bf(a5) << 16);
    pk.w = (unsigned)f2bf(a6) | ((unsigned)f2bf(a7) << 16);
    *reinterpret_cast<uint4*>(&tile[grp][wv * 8 + h][o * 8]) = pk;
  }
  __syncthreads();

  // ---- MFMA phase: pair splits columns (wave wv -> t = 2wv, 2wv+1)
  int m = lane & 15;
  int q = lane >> 4;
  bool active = (base < NN);
  f32x4 acc[2];
  if (active) {
    long rowm = base + m;
    if (rowm >= NN) rowm = NN - 1;  // clamped dup read; store predicated
    bf16x8 af[4];
    af[0] = *reinterpret_cast<const bf16x8*>(&tile[grp][m][q * 8]);
    af[1] = *reinterpret_cast<const bf16x8*>(&tile[grp][m][32 + q * 8]);
    const unsigned short* hrow = feat + rowm * 64;
    af[2] = *(const bf16x8*)(hrow + q * 8);       // k 64..95
    af[3] = *(const bf16x8*)(hrow + 32 + q * 8);  // k 96..127

#pragma unroll
    for (int tt = 0; tt < 2; ++tt) {
      int t = wv * 2 + tt;
      float bv = bias[t * 16 + m];
      acc[tt][0] = bv;
      acc[tt][1] = bv;
      acc[tt][2] = bv;
      acc[tt][3] = bv;
      const unsigned short* wrow = Wt + (size_t)(t * 16 + m) * 128 + q * 8;
#pragma unroll
      for (int s = 0; s < 4; ++s) {
        bf16x8 bfm = *(const bf16x8*)(wrow + s * 32);
        acc[tt] = __builtin_amdgcn_mfma_f32_16x16x32_bf16(af[s], bfm, acc[tt],
                                                          0, 0, 0);
      }
    }

    // ---- epilogue
    if (POOL) {
#pragma unroll
      for (int r = 0; r < 4; ++r) {
#pragma unroll
        for (int tt = 0; tt < 2; ++tt) {
          psm[grp][q * 4 + r][(wv * 2 + tt) * 16 + m] = fmaxf(acc[tt][r], 0.f);
        }
      }
    } else {
#pragma unroll
      for (int r = 0; r < 4; ++r) {
        long rowc = base + q * 4 + r;
        if (rowc < NN) {
          unsigned short* orow = out + rowc * 64;
#pragma unroll
          for (int tt = 0; tt < 2; ++tt) {
            orow[(wv * 2 + tt) * 16 + m] = f2bf(fmaxf(acc[tt][r], 0.f));
          }
        }
      }
    }
  }

  if (POOL) {
    __syncthreads();
    if (tid < 128) {  // one walker per (group, column)
      int g2 = tid >> 6;
      int c = tid & 63;
      long tbase = ((long)blockIdx.x * 2 + g2) * 16;
      if (tbase < NN) {
        float run = 0.f;
        int g = batch[tbase];
        for (int i = 0; i < 16; ++i) {
          long rowi = tbase + i;
          if (rowi >= NN) break;
          int gi = batch[rowi];
          if (gi != g) {
            atomicAdd(&pooled[(size_t)g * 64 + c], run);
            run = 0.f;
            g = gi;
          }
          run += psm[g2][i][c];
        }
        atomicAdd(&pooled[(size_t)g * 64 + c], run);
      }
    }
  }
}

// ---------------- head: out[g,o] = bo[o] + pooled[g,:] @ Wo[:,o] -----------
__global__ __launch_bounds__(256) void head_kernel(
    const float* __restrict__ pooled, const float* __restrict__ Wo,
    const float* __restrict__ bo, float* __restrict__ out) {
  int id = blockIdx.x * 256 + threadIdx.x;
  if (id >= NG * NO) return;
  int g = id >> 4, o = id & 15;
  float acc = bo[o];
  const float* p = pooled + (size_t)g * 64;
#pragma unroll
  for (int k = 0; k < 64; ++k) acc += p[k] * Wo[k * 16 + o];
  out[id] = acc;
}

extern "C" void kernel_launch(void* const* d_in, const int* in_sizes, int n_in,
                              void* d_out, int out_size, void* d_ws,
                              size_t ws_size, hipStream_t stream) {
  const float* x = (const float*)d_in[0];
  const int* ei = (const int*)d_in[1];
  const int* batch = (const int*)d_in[2];
  const float* Wl1 = (const float*)d_in[3];
  const float* Wr1 = (const float*)d_in[4];
  const float* b1 = (const float*)d_in[5];
  const float* Wl2 = (const float*)d_in[6];
  const float* Wr2 = (const float*)d_in[7];
  const float* b2 = (const float*)d_in[8];
  const float* Wo = (const float*)d_in[9];
  const float* bo = (const float*)d_in[10];
  float* out = (float*)d_out;

  // Workspace (~22.7 MB):
  unsigned short* x_bf = (unsigned short*)d_ws;     // NN*64 bf16 (6.4 MB)
  unsigned short* h1_bf = x_bf + (size_t)NN * 64;   // NN*64 bf16 (6.4 MB)
  unsigned short* col = h1_bf + (size_t)NN * 64;    // KB*BCAP ushort (3.1MB)
  unsigned short* Wt1 = col + (size_t)KB * BCAP;    // 64*128 bf16
  unsigned short* Wt2 = Wt1 + 64 * 128;             // 64*128 bf16
  unsigned int* ebuf = (unsigned int*)(Wt2 + 64 * 128);  // KB*BCAP (6.27MB)
  unsigned int* meta = ebuf + (size_t)KB * BCAP;    // NN
  int* bcount = (int*)(meta + NN);                  // KB
  float* pooled = (float*)(bcount + KB);            // NG*64 (contig w/bcount)

  // one memset covers bcount + pooled (contiguous)
  hipMemsetAsync(bcount, 0, KB * sizeof(int) + (size_t)NG * 64 * sizeof(float),
                 stream);

  const int fused_blocks = (NN + 31) / 32;  // 1563: 2 groups x 16 rows

  // prep: x->bf16 | weight transpose | bucket scatter (one role-split launch)
  prep_all<<<CVT_BLK + WP_BLK + SBLK, 256, 0, stream>>>(
      x, x_bf, Wl1, Wr1, Wl2, Wr2, Wt1, Wt2, ei, bcount, ebuf);

  // CSR finalize
  bucket_sort<<<KB, 512, 0, stream>>>(ebuf, bcount, meta, col);

  // Layer 1: fused gather+GEMM, writes h1
  sage_fused<false><<<fused_blocks, 256, 0, stream>>>(
      x_bf, meta, col, Wt1, b1, h1_bf, batch, pooled);

  // Layer 2: fused gather+GEMM+pool (h2 never materialized)
  sage_fused<true><<<fused_blocks, 256, 0, stream>>>(
      h1_bf, meta, col, Wt2, b2, nullptr, batch, pooled);

  // Head from pooled (128 KB)
  head_kernel<<<(NG * NO + 255) / 256, 256, 0, stream>>>(pooled, Wo, bo, out);
}